// Round 1
// baseline (10811.348 us; speedup 1.0000x reference)
//
#include <hip/hip_runtime.h>

// LSTM: T=2048, B=32, E=512, H=512, fp32 in/out.
// Phase 1 (lstm_prep): embeds fp32 -> bf16 in ws; init h_buf[0]=h_0; zero flags.
// Phase 2 (lstm_rec): 128 persistent WGs, each owns 4 h-columns (16 gate cols).
//   Per step: gates = [emb_t | h_t] (bf16) @ [Wx;Wh] slice (bf16, LDS) via MFMA,
//   fp32 epilogue, h broadcast through L3 with agent-scope (sc1) atomics.

#define T_STEPS 2048
#define BATCH   32
#define EDIM    512
#define HDIM    512
#define NW      128   // recurrent workgroups
#define NJ      4     // h-columns per WG
#define NCOL    16    // packed gate columns per WG (4 gates * NJ)
#define WG_THREADS 128
#define BSTRIDE 1032  // 1024 + 8 pad (keeps 16B align, kills LDS bank conflicts)

typedef unsigned int       u32;
typedef unsigned long long u64;
typedef unsigned short     u16;
typedef float  floatx4 __attribute__((ext_vector_type(4)));
typedef __bf16 bf16x8  __attribute__((ext_vector_type(8)));

union BF16U { __bf16 b; u16 u; };

__device__ __forceinline__ u16 f2bf(float f) { BF16U x; x.b = (__bf16)f; return x.u; }

__device__ __forceinline__ float fast_sigmoid(float x) {
  return 1.0f / (1.0f + __expf(-x));
}
__device__ __forceinline__ float fast_tanh(float x) {
  float e = __expf(-2.0f * fabsf(x));       // e in (0,1], no overflow
  float t = (1.0f - e) / (1.0f + e);
  return x >= 0.0f ? t : -t;
}

// ---------------------------------------------------------------- phase 1
__global__ void lstm_prep(const float* __restrict__ emb, u16* __restrict__ embb,
                          const float* __restrict__ h0, u16* __restrict__ hb0,
                          u32* __restrict__ flags) {
  const size_t n4 = (size_t)T_STEPS * BATCH * EDIM / 4;
  size_t stride = (size_t)gridDim.x * blockDim.x;
  size_t gid = (size_t)blockIdx.x * blockDim.x + threadIdx.x;
  for (size_t i = gid; i < n4; i += stride) {
    float4 v = ((const float4*)emb)[i];
    ushort4 o;
    o.x = f2bf(v.x); o.y = f2bf(v.y); o.z = f2bf(v.z); o.w = f2bf(v.w);
    ((ushort4*)embb)[i] = o;
  }
  if (gid < (size_t)BATCH * HDIM) hb0[gid] = f2bf(h0[gid]);
  if (gid < NW) flags[gid] = 0u;
}

// ---------------------------------------------------------------- phase 2
__global__ void __launch_bounds__(WG_THREADS)
lstm_rec(const u16* __restrict__ embb,
         const float* __restrict__ c0,
         const float* __restrict__ Wx0, const float* __restrict__ Wh0, const float* __restrict__ b0,
         const float* __restrict__ Wx1, const float* __restrict__ Wh1, const float* __restrict__ b1,
         const float* __restrict__ Wx2, const float* __restrict__ Wh2, const float* __restrict__ b2,
         const float* __restrict__ Wx3, const float* __restrict__ Wh3, const float* __restrict__ b3,
         u16* __restrict__ hbuf,            // [2][BATCH*HDIM] bf16
         u32* __restrict__ flags,           // [NW]
         float* __restrict__ out) {
  __shared__ __align__(16) __bf16 Blds[NCOL][BSTRIDE];  // [packed col][k=E|H], bf16
  __shared__ float gbuf[BATCH][NCOL + 1];               // fp32 pre-activations

  const int tid    = threadIdx.x;
  const int w      = blockIdx.x;
  const int j0     = w * NJ;            // first h-column owned by this WG
  const int lane   = tid & 63;
  const int waveid = tid >> 6;          // 0..1 = M-tile (batch half)
  const int nlo    = lane & 15;
  const int q      = lane >> 4;
  const int mrow   = waveid * 16 + nlo; // batch row this lane loads A for

  const float* Wx[4] = {Wx0, Wx1, Wx2, Wx3};
  const float* Wh[4] = {Wh0, Wh1, Wh2, Wh3};

  // ---- stage weight slice into LDS as bf16: Blds[g*4+c][k] =
  //      k<512 ? Wx_g[k][j0+c] : Wh_g[k-512][j0+c]
  for (int g = 0; g < 4; ++g) {
    for (int base = 0; base < EDIM; base += WG_THREADS) {
      int kk = base + tid;
      float4 wx = *(const float4*)(Wx[g] + (size_t)kk * HDIM + j0);
      float4 wh = *(const float4*)(Wh[g] + (size_t)kk * HDIM + j0);
      Blds[g*NJ+0][kk] = (__bf16)wx.x;  Blds[g*NJ+0][EDIM+kk] = (__bf16)wh.x;
      Blds[g*NJ+1][kk] = (__bf16)wx.y;  Blds[g*NJ+1][EDIM+kk] = (__bf16)wh.y;
      Blds[g*NJ+2][kk] = (__bf16)wx.z;  Blds[g*NJ+2][EDIM+kk] = (__bf16)wh.z;
      Blds[g*NJ+3][kk] = (__bf16)wx.w;  Blds[g*NJ+3][EDIM+kk] = (__bf16)wh.w;
    }
  }

  // ---- per-thread epilogue state: thread -> (batch eb, column ej)
  const int eb = tid >> 2;        // 0..31
  const int ej = tid & 3;         // 0..3
  const int jg = j0 + ej;         // global h column
  float cst = c0[(size_t)eb * HDIM + jg];
  const float bgv = b0[jg], biv = b1[jg], bfv = b2[jg], bov = b3[jg];

  __syncthreads();

  for (int t = 0; t < T_STEPS; ++t) {
    // ---- wait until every WG has published h_t (flags >= t); wave 0 polls
    if (waveid == 0) {
      const u64* f8 = (const u64*)flags;  // 64 lanes x 2 flags each = 128
      for (;;) {
        u64 v = __hip_atomic_load(&f8[lane], __ATOMIC_RELAXED, __HIP_MEMORY_SCOPE_AGENT);
        int ok = ((u32)v >= (u32)t) && ((u32)(v >> 32) >= (u32)t);
        if (__all(ok)) break;
        __builtin_amdgcn_s_sleep(1);
      }
    }
    __syncthreads();   // releases all waves; also orders gbuf reuse (WAR)

    const u16* hcur  = hbuf + (size_t)(t & 1) * (BATCH * HDIM);
    u16*       hnext = hbuf + (size_t)((t + 1) & 1) * (BATCH * HDIM);

    // ---- gates(pre) = [emb_t | h_t] @ Bslice  (K = 1024, two accs for ILP)
    floatx4 acc0 = {0.f, 0.f, 0.f, 0.f};
    floatx4 acc1 = {0.f, 0.f, 0.f, 0.f};
    const u16* erow = embb + ((size_t)t * BATCH + mrow) * EDIM;
#pragma unroll
    for (int s = 0; s < 16; s += 2) {
      int k0 = s * 32 + q * 8;
      int k1 = (s + 1) * 32 + q * 8;
      bf16x8 a0 = *reinterpret_cast<const bf16x8*>(erow + k0);
      bf16x8 a1 = *reinterpret_cast<const bf16x8*>(erow + k1);
      bf16x8 w0 = *reinterpret_cast<const bf16x8*>(&Blds[nlo][k0]);
      bf16x8 w1 = *reinterpret_cast<const bf16x8*>(&Blds[nlo][k1]);
      acc0 = __builtin_amdgcn_mfma_f32_16x16x32_bf16(a0, w0, acc0, 0, 0, 0);
      acc1 = __builtin_amdgcn_mfma_f32_16x16x32_bf16(a1, w1, acc1, 0, 0, 0);
    }
    // h part: agent-scope (sc1, L2-bypass) loads — coherent across XCDs
    const u64* hrow = (const u64*)(hcur + (size_t)mrow * HDIM);
#pragma unroll
    for (int s = 0; s < 16; s += 2) {
      int k0 = s * 32 + q * 8;       // bf16 index in [0,512)
      int k1 = (s + 1) * 32 + q * 8;
      union { u64 qv[2]; bf16x8 v; } ua, ub;
      ua.qv[0] = __hip_atomic_load(&hrow[(k0 >> 2) + 0], __ATOMIC_RELAXED, __HIP_MEMORY_SCOPE_AGENT);
      ua.qv[1] = __hip_atomic_load(&hrow[(k0 >> 2) + 1], __ATOMIC_RELAXED, __HIP_MEMORY_SCOPE_AGENT);
      ub.qv[0] = __hip_atomic_load(&hrow[(k1 >> 2) + 0], __ATOMIC_RELAXED, __HIP_MEMORY_SCOPE_AGENT);
      ub.qv[1] = __hip_atomic_load(&hrow[(k1 >> 2) + 1], __ATOMIC_RELAXED, __HIP_MEMORY_SCOPE_AGENT);
      bf16x8 w0 = *reinterpret_cast<const bf16x8*>(&Blds[nlo][EDIM + k0]);
      bf16x8 w1 = *reinterpret_cast<const bf16x8*>(&Blds[nlo][EDIM + k1]);
      acc0 = __builtin_amdgcn_mfma_f32_16x16x32_bf16(ua.v, w0, acc0, 0, 0, 0);
      acc1 = __builtin_amdgcn_mfma_f32_16x16x32_bf16(ub.v, w1, acc1, 0, 0, 0);
    }
    // C/D layout: col = lane&15, row = (lane>>4)*4 + reg  (row = batch in M-tile)
#pragma unroll
    for (int r = 0; r < 4; ++r)
      gbuf[waveid * 16 + q * 4 + r][nlo] = acc0[r] + acc1[r];
    __syncthreads();

    // ---- fp32 epilogue: thread owns (eb, jg)
    float gv = fast_tanh   (gbuf[eb][ej]      + bgv);
    float iv = fast_sigmoid(gbuf[eb][4 + ej]  + biv);
    float fv = fast_sigmoid(gbuf[eb][8 + ej]  + bfv);
    float ov = fast_sigmoid(gbuf[eb][12 + ej] + bov);
    cst = gv * iv + cst * fv;
    float hv = fast_tanh(cst) * ov;

    out[((size_t)t * BATCH + eb) * HDIM + jg] = hv;          // seq
    __hip_atomic_store(hnext + (size_t)eb * HDIM + jg, f2bf(hv),
                       __ATOMIC_RELAXED, __HIP_MEMORY_SCOPE_AGENT);
    if (t == T_STEPS - 1) {
      const size_t seqN = (size_t)T_STEPS * BATCH * HDIM;
      out[seqN + (size_t)eb * HDIM + jg] = hv;               // h_T
      out[seqN + (size_t)BATCH * HDIM + (size_t)eb * HDIM + jg] = cst;  // c_T
    }
    __syncthreads();   // drains all waves' h stores (vmcnt) before publish
    if (tid == 0)
      __hip_atomic_store(&flags[w], (u32)(t + 1),
                         __ATOMIC_RELAXED, __HIP_MEMORY_SCOPE_AGENT);
  }
}

// ---------------------------------------------------------------- launch
extern "C" void kernel_launch(void* const* d_in, const int* in_sizes, int n_in,
                              void* d_out, int out_size, void* d_ws, size_t ws_size,
                              hipStream_t stream) {
  const float* emb = (const float*)d_in[0];
  const float* h0  = (const float*)d_in[1];
  const float* c0  = (const float*)d_in[2];
  const float* Wgx = (const float*)d_in[3];
  const float* Wgh = (const float*)d_in[4];
  const float* bg  = (const float*)d_in[5];
  const float* Wix = (const float*)d_in[6];
  const float* Wih = (const float*)d_in[7];
  const float* bi  = (const float*)d_in[8];
  const float* Wfx = (const float*)d_in[9];
  const float* Wfh = (const float*)d_in[10];
  const float* bf  = (const float*)d_in[11];
  const float* Wox = (const float*)d_in[12];
  const float* Woh = (const float*)d_in[13];
  const float* bo  = (const float*)d_in[14];
  float* out = (float*)d_out;

  char* ws = (char*)d_ws;
  const size_t embb_bytes = (size_t)T_STEPS * BATCH * EDIM * 2;   // 67,108,864
  u16* embb  = (u16*)ws;
  u16* hbuf  = (u16*)(ws + embb_bytes);                           // 2*32768 B
  u32* flags = (u32*)(ws + embb_bytes + 2 * (size_t)BATCH * HDIM * 2);

  lstm_prep<<<4096, 256, 0, stream>>>(emb, embb, h0, hbuf, flags);
  lstm_rec<<<NW, WG_THREADS, 0, stream>>>(embb, c0,
                                          Wgx, Wgh, bg,
                                          Wix, Wih, bi,
                                          Wfx, Wfh, bf,
                                          Wox, Woh, bo,
                                          hbuf, flags, out);
}